// Round 3
// baseline (1373.769 us; speedup 1.0000x reference)
//
#include <hip/hip_runtime.h>
#include <math.h>

#define GH 300
#define GW 400
#define GHW (GH * GW)

// ---------------------------------------------------------------------------
// Init: ch0 <- hmax acc (-inf), ch1 <- isum acc (0), ch2 <- cnt acc (0),
// ch3/ch4 <- polyline channels (0).
// ---------------------------------------------------------------------------
__global__ __launch_bounds__(256) void init_kernel(float* __restrict__ out) {
    int i = blockIdx.x * blockDim.x + threadIdx.x;
    if (i < GHW) {
        out[0 * GHW + i] = -INFINITY;
        out[1 * GHW + i] = 0.0f;
        out[2 * GHW + i] = 0.0f;
        out[3 * GHW + i] = 0.0f;
        out[4 * GHW + i] = 0.0f;
    }
}

// Race-safe float atomic max (signed-max for >=0, unsigned-min for <0).
// Each op is monotone in float order under either path, so interleavings are safe.
__device__ __forceinline__ void atomicMaxFloat(float* addr, float val) {
    if (val >= 0.0f) {
        atomicMax((int*)addr, __float_as_int(val));
    } else {
        atomicMin((unsigned int*)addr, (unsigned int)__float_as_int(val));
    }
}

// ---------------------------------------------------------------------------
// Lidar scatter: one thread per point.
// Binning mimics XLA's div-by-constant -> mul-by-reciprocal canonicalization:
//   px = int32(trunc((x - X0) * 10.0f))   [f32 sub, f32 mul, no FMA]
// ---------------------------------------------------------------------------
__global__ __launch_bounds__(256) void lidar_kernel(const float4* __restrict__ pts, int n,
                                                    float* __restrict__ out) {
    int i = blockIdx.x * blockDim.x + threadIdx.x;
    if (i >= n) return;
    float4 p = pts[i];
    if (!(p.x >= -20.0f && p.x < 20.0f && p.y >= -10.0f && p.y < 30.0f)) return;
    float qx = __fmul_rn(__fsub_rn(p.x, -20.0f), 10.0f);  // (x+20)*10, XLA semantics
    float qy = __fmul_rn(__fsub_rn(p.y, -10.0f), 10.0f);  // (y+10)*10
    int px = (int)qx;  // trunc toward zero == astype(int32); qx >= 0 for in-box
    int py = (int)qy;
    px = min(max(px, 0), GW - 1);
    py = min(max(py, 0), GH - 1);
    int idx = py * GW + px;
    atomicMaxFloat(&out[0 * GHW + idx], p.z);   // hmax
    atomicAdd(&out[1 * GHW + idx], p.w);        // intensity sum
    atomicAdd(&out[2 * GHW + idx], 1.0f);       // count (exact small ints in f32)
}

// ---------------------------------------------------------------------------
// Finalize lidar channels in place. f32 with reciprocal-mul for constant
// denominators (matches XLA); true f32 division for the runtime denominator.
// ---------------------------------------------------------------------------
__global__ __launch_bounds__(256) void finalize_kernel(float* __restrict__ out) {
    int i = blockIdx.x * blockDim.x + threadIdx.x;
    if (i >= GHW) return;
    float hm = out[0 * GHW + i];
    float isum = out[1 * GHW + i];
    float c = out[2 * GHW + i];
    if (hm == -INFINITY) hm = 0.0f;  // jnp.where(isneginf(hmax), 0, hmax)
    const float inv7 = 1.0f / 7.0f;
    const float inv255 = 1.0f / 255.0f;
    const float invlog129 = 1.0f / 4.8598124043616719e+00f;  // 1/log(129)
    float h = fminf(fmaxf(__fmul_rn(__fadd_rn(hm, 3.0f), inv7), 0.0f), 1.0f);
    float im = (c > 0.0f) ? __fdiv_rn(isum, fmaxf(c, 1.0f)) : 0.0f;
    float ich = fminf(fmaxf(__fmul_rn(im, inv255), 0.0f), 1.0f);
    float dd = fminf(fmaxf(__fmul_rn(log1pf(c), invlog129), 0.0f), 1.0f);
    out[0 * GHW + i] = h;
    out[1 * GHW + i] = ich;
    out[2 * GHW + i] = dd;
}

// ---------------------------------------------------------------------------
// Polyline raster (unchanged from round 2 — empirically matched the ref).
// One 64-thread block per segment; lanes stride over k in [0, dmax];
// k > dmax duplicates k==dmax (t==1 exactly) so the 512-sample set is covered.
// ---------------------------------------------------------------------------
__global__ __launch_bounds__(64) void polyline_kernel(const float2* __restrict__ pts, int npts,
                                                      const float* __restrict__ ego, int use_ego,
                                                      float* __restrict__ out_ch) {
    int seg = blockIdx.x;
    if (seg >= npts - 1) return;
    float2 P0 = pts[seg];
    float2 P1 = pts[seg + 1];
    if (use_ego) {
        float yaw = ego[2];
        float cy = cosf(-yaw), sy = sinf(-yaw);
        float ex = ego[0], ey = ego[1];
        float d0x = __fsub_rn(P0.x, ex), d0y = __fsub_rn(P0.y, ey);
        float d1x = __fsub_rn(P1.x, ex), d1y = __fsub_rn(P1.y, ey);
        P0.x = __fsub_rn(__fmul_rn(d0x, cy), __fmul_rn(d0y, sy));
        P0.y = __fadd_rn(__fmul_rn(d0x, sy), __fmul_rn(d0y, cy));
        P1.x = __fsub_rn(__fmul_rn(d1x, cy), __fmul_rn(d1y, sy));
        P1.y = __fadd_rn(__fmul_rn(d1x, sy), __fmul_rn(d1y, cy));
    }
    double ax = trunc(__ddiv_rn(__dadd_rn((double)P0.x, 20.0), 0.1));
    double ay = trunc(__ddiv_rn(__dadd_rn((double)P0.y, 10.0), 0.1));
    double bx = trunc(__ddiv_rn(__dadd_rn((double)P1.x, 20.0), 0.1));
    double by = trunc(__ddiv_rn(__dadd_rn((double)P1.y, 10.0), 0.1));
    bool inA = (ax >= 0.0) && (ax < (double)GW) && (ay >= 0.0) && (ay < (double)GH);
    bool inB = (bx >= 0.0) && (bx < (double)GW) && (by >= 0.0) && (by < (double)GH);
    if (!(inA || inB)) return;  // val==0 -> scatter-max is a no-op
    ax = fmin(fmax(ax, 0.0), (double)(GW - 1));
    ay = fmin(fmax(ay, 0.0), (double)(GH - 1));
    bx = fmin(fmax(bx, 0.0), (double)(GW - 1));
    by = fmin(fmax(by, 0.0), (double)(GH - 1));
    double dx = __dsub_rn(bx, ax);
    double dy = __dsub_rn(by, ay);
    double dmax = fmax(fabs(dx), fabs(dy));  // exact small integer
    double denom = fmax(dmax, 1.0);
    int kmax = (int)dmax;  // <= 399 < K_SAMPLES
    for (int k = threadIdx.x; k <= kmax; k += blockDim.x) {
        double t = __ddiv_rn(fmin((double)k, dmax), denom);
        double ptx = __dadd_rn(ax, __dmul_rn(t, dx));
        double pty = __dadd_rn(ay, __dmul_rn(t, dy));
        int cx = (int)rint(ptx);  // half-to-even
        int cc = (int)rint(pty);
#pragma unroll
        for (int oy = -1; oy <= 1; ++oy) {
#pragma unroll
            for (int ox = -1; ox <= 1; ++ox) {
                int xx = cx + ox;
                int yy = cc + oy;
                // JAX normalizes negative indices (wrap), then drops OOB
                if (xx < 0) xx += GW;
                if (yy < 0) yy += GH;
                if (xx >= 0 && xx < GW && yy >= 0 && yy < GH) {
                    out_ch[yy * GW + xx] = 1.0f;  // benign race: all write 1.0
                }
            }
        }
    }
}

extern "C" void kernel_launch(void* const* d_in, const int* in_sizes, int n_in,
                              void* d_out, int out_size, void* d_ws, size_t ws_size,
                              hipStream_t stream) {
    const float* lidar = (const float*)d_in[0];
    const float* traj = (const float*)d_in[1];
    const float* osm = (const float*)d_in[2];
    const float* ego = (const float*)d_in[3];
    float* out = (float*)d_out;

    int n_lidar = in_sizes[0] / 4;
    int n_traj = in_sizes[1] / 2;
    int n_osm = in_sizes[2] / 2;

    init_kernel<<<(GHW + 255) / 256, 256, 0, stream>>>(out);
    lidar_kernel<<<(n_lidar + 255) / 256, 256, 0, stream>>>((const float4*)lidar, n_lidar, out);
    finalize_kernel<<<(GHW + 255) / 256, 256, 0, stream>>>(out);
    polyline_kernel<<<n_traj - 1, 64, 0, stream>>>((const float2*)traj, n_traj, nullptr, 0,
                                                   out + 3 * GHW);
    polyline_kernel<<<n_osm - 1, 64, 0, stream>>>((const float2*)osm, n_osm, ego, 1,
                                                  out + 4 * GHW);
}

// Round 4
// 223.010 us; speedup vs baseline: 6.1601x; 6.1601x over previous
//
#include <hip/hip_runtime.h>
#include <math.h>

#define GH 300
#define GW 400
#define GHW (GH * GW)

// Tile grid: 16x16 cells per tile
#define TCOLS 25              // 400/16
#define TROWS 19              // ceil(300/16)
#define T_TILES (TCOLS * TROWS)  // 475
#define B1 256                // phase-1 blocks

// ---------------------------------------------------------------------------
// Shared binning (bit-identical to the verified round-3 semantics):
// XLA canonicalization of (x - X0)/RES -> (x + 20) * 10 in f32, no FMA.
// ---------------------------------------------------------------------------
__device__ __forceinline__ bool bin_point(float x, float y, int& px, int& py) {
    if (!(x >= -20.0f && x < 20.0f && y >= -10.0f && y < 30.0f)) return false;
    float qx = __fmul_rn(__fsub_rn(x, -20.0f), 10.0f);
    float qy = __fmul_rn(__fsub_rn(y, -10.0f), 10.0f);
    px = min(max((int)qx, 0), GW - 1);
    py = min(max((int)qy, 0), GH - 1);
    return true;
}

// ---------------------------------------------------------------------------
// Pass A: per-block tile histograms (LDS only; non-atomic global writes).
// ---------------------------------------------------------------------------
__global__ __launch_bounds__(256) void hist_kernel(const float4* __restrict__ pts, int n,
                                                   int per_block, unsigned* __restrict__ hist) {
    __shared__ unsigned cnt[T_TILES];
    for (int t = threadIdx.x; t < T_TILES; t += 256) cnt[t] = 0;
    __syncthreads();
    int start = blockIdx.x * per_block;
    int end = min(start + per_block, n);
    for (int i = start + (int)threadIdx.x; i < end; i += 256) {
        float4 p = pts[i];
        int px, py;
        if (bin_point(p.x, p.y, px, py)) {
            int tile = (py >> 4) * TCOLS + (px >> 4);
            atomicAdd(&cnt[tile], 1u);
        }
    }
    __syncthreads();
    for (int t = threadIdx.x; t < T_TILES; t += 256)
        hist[blockIdx.x * T_TILES + t] = cnt[t];
}

// ---------------------------------------------------------------------------
// Scan: per-(block,tile) exclusive offsets along blocks; tile prefix sums.
// hist[b*T+t] <- sum_{b'<b} cnt[b'][t];  tileStart[t] <- prefix over tiles.
// ---------------------------------------------------------------------------
__global__ __launch_bounds__(512) void scan_kernel(unsigned* __restrict__ hist,
                                                   unsigned* __restrict__ tileStart) {
    __shared__ unsigned tot[T_TILES];
    int t = threadIdx.x;
    if (t < T_TILES) {
        unsigned run = 0;
        for (int b = 0; b < B1; ++b) {
            unsigned c = hist[b * T_TILES + t];
            hist[b * T_TILES + t] = run;
            run += c;
        }
        tot[t] = run;
    }
    __syncthreads();
    if (threadIdx.x == 0) {
        unsigned acc = 0;
        for (int i = 0; i < T_TILES; ++i) {
            tileStart[i] = acc;
            acc += tot[i];
        }
        tileStart[T_TILES] = acc;
    }
}

// ---------------------------------------------------------------------------
// Pass B: scatter packed records into tile-sorted order. LDS cursors give
// unique slots (no global atomics). Record: [z16 | i16 | local8] in a u64.
//   z16 = round((z+3)*65535/7) clamped  (h tolerance 2e-2 >> 1.5e-5 quant err)
//   i16 = round(inten*256) clamped      (8.8 fixed; imean tolerance ~5)
// ---------------------------------------------------------------------------
__global__ __launch_bounds__(256) void scatter_kernel(const float4* __restrict__ pts, int n,
                                                      int per_block,
                                                      const unsigned* __restrict__ hist,
                                                      const unsigned* __restrict__ tileStart,
                                                      unsigned long long* __restrict__ rec) {
    __shared__ unsigned cur[T_TILES];
    for (int t = threadIdx.x; t < T_TILES; t += 256)
        cur[t] = tileStart[t] + hist[blockIdx.x * T_TILES + t];
    __syncthreads();
    int start = blockIdx.x * per_block;
    int end = min(start + per_block, n);
    for (int i = start + (int)threadIdx.x; i < end; i += 256) {
        float4 p = pts[i];
        int px, py;
        if (bin_point(p.x, p.y, px, py)) {
            int tile = (py >> 4) * TCOLS + (px >> 4);
            int local = ((py & 15) << 4) | (px & 15);
            int z16 = (int)rintf(__fmul_rn(__fsub_rn(p.z, -3.0f), 65535.0f / 7.0f));
            z16 = min(max(z16, 0), 65535);
            int i16 = (int)rintf(__fmul_rn(p.w, 256.0f));
            i16 = min(max(i16, 0), 65535);
            unsigned pos = atomicAdd(&cur[tile], 1u);
            rec[pos] = ((unsigned long long)(unsigned)z16 << 32) |
                       ((unsigned long long)(unsigned)i16 << 16) | (unsigned)local;
        }
    }
}

// ---------------------------------------------------------------------------
// Accumulate per tile in LDS, finalize h/i/d, store (no atomics beyond LDS).
// ic packs (cnt << 40) | sum_i16 — overflow impossible: 4e6*65280 < 2^40.
// ---------------------------------------------------------------------------
__global__ __launch_bounds__(256) void accum_kernel(const unsigned long long* __restrict__ rec,
                                                    const unsigned* __restrict__ tileStart,
                                                    float* __restrict__ out) {
    __shared__ unsigned zmax[256];           // 0 = empty; else z16+1
    __shared__ unsigned long long ic[256];   // (cnt<<40) | sum_i16
    zmax[threadIdx.x] = 0;
    ic[threadIdx.x] = 0;
    __syncthreads();
    unsigned s = tileStart[blockIdx.x];
    unsigned e = tileStart[blockIdx.x + 1];
    for (unsigned i = s + threadIdx.x; i < e; i += 256) {
        unsigned long long r = rec[i];
        int local = (int)(r & 0xFF);
        unsigned z16 = (unsigned)(r >> 32) & 0xFFFFu;
        unsigned long long i16 = (r >> 16) & 0xFFFFull;
        atomicMax(&zmax[local], z16 + 1u);
        atomicAdd(&ic[local], (1ull << 40) | i16);
    }
    __syncthreads();
    int l = threadIdx.x;
    int trow = blockIdx.x / TCOLS, tcol = blockIdx.x % TCOLS;
    int gy = trow * 16 + (l >> 4);
    int gx = tcol * 16 + (l & 15);
    if (gy < GH) {
        const float inv7 = 1.0f / 7.0f;
        const float invlog129 = 1.0f / 4.8598124043616719e+00f;  // 1/log(129)
        unsigned long long v = ic[l];
        float h, ich, dd;
        if (v == 0) {
            // empty cell: hmax -inf -> 0 -> h = clip(3/7); i = 0; d = 0
            h = fminf(fmaxf(__fmul_rn(3.0f, inv7), 0.0f), 1.0f);
            ich = 0.0f;
            dd = 0.0f;
        } else {
            unsigned cnt = (unsigned)(v >> 40);
            float sum16 = (float)(v & ((1ull << 40) - 1));  // sum of inten*256
            h = fminf((float)(zmax[l] - 1u) * (1.0f / 65535.0f), 1.0f);
            // imean/255 = sum16 / (cnt * 256 * 255)
            ich = fminf(__fdiv_rn(sum16, __fmul_rn((float)cnt, 65280.0f)), 1.0f);
            dd = fminf(__fmul_rn(log1pf((float)cnt), invlog129), 1.0f);
        }
        int idx = gy * GW + gx;
        out[0 * GHW + idx] = h;
        out[1 * GHW + idx] = ich;
        out[2 * GHW + idx] = dd;
    }
}

// ---------------------------------------------------------------------------
// Zero only the polyline channels (fast path; accum writes ch0..2 fully).
// ---------------------------------------------------------------------------
__global__ __launch_bounds__(256) void init34_kernel(float* __restrict__ out) {
    int i = blockIdx.x * blockDim.x + threadIdx.x;
    if (i < GHW) {
        out[3 * GHW + i] = 0.0f;
        out[4 * GHW + i] = 0.0f;
    }
}

// ======================== fallback (round-3) path ==========================
__global__ __launch_bounds__(256) void init_kernel(float* __restrict__ out) {
    int i = blockIdx.x * blockDim.x + threadIdx.x;
    if (i < GHW) {
        out[0 * GHW + i] = -INFINITY;
        out[1 * GHW + i] = 0.0f;
        out[2 * GHW + i] = 0.0f;
        out[3 * GHW + i] = 0.0f;
        out[4 * GHW + i] = 0.0f;
    }
}

__device__ __forceinline__ void atomicMaxFloat(float* addr, float val) {
    if (val >= 0.0f) {
        atomicMax((int*)addr, __float_as_int(val));
    } else {
        atomicMin((unsigned int*)addr, (unsigned int)__float_as_int(val));
    }
}

__global__ __launch_bounds__(256) void lidar_kernel(const float4* __restrict__ pts, int n,
                                                    float* __restrict__ out) {
    int i = blockIdx.x * blockDim.x + threadIdx.x;
    if (i >= n) return;
    float4 p = pts[i];
    int px, py;
    if (!bin_point(p.x, p.y, px, py)) return;
    int idx = py * GW + px;
    atomicMaxFloat(&out[0 * GHW + idx], p.z);
    atomicAdd(&out[1 * GHW + idx], p.w);
    atomicAdd(&out[2 * GHW + idx], 1.0f);
}

__global__ __launch_bounds__(256) void finalize_kernel(float* __restrict__ out) {
    int i = blockIdx.x * blockDim.x + threadIdx.x;
    if (i >= GHW) return;
    float hm = out[0 * GHW + i];
    float isum = out[1 * GHW + i];
    float c = out[2 * GHW + i];
    if (hm == -INFINITY) hm = 0.0f;
    const float inv7 = 1.0f / 7.0f;
    const float inv255 = 1.0f / 255.0f;
    const float invlog129 = 1.0f / 4.8598124043616719e+00f;
    float h = fminf(fmaxf(__fmul_rn(__fadd_rn(hm, 3.0f), inv7), 0.0f), 1.0f);
    float im = (c > 0.0f) ? __fdiv_rn(isum, fmaxf(c, 1.0f)) : 0.0f;
    float ich = fminf(fmaxf(__fmul_rn(im, inv255), 0.0f), 1.0f);
    float dd = fminf(fmaxf(__fmul_rn(log1pf(c), invlog129), 0.0f), 1.0f);
    out[0 * GHW + i] = h;
    out[1 * GHW + i] = ich;
    out[2 * GHW + i] = dd;
}

// ---------------------------------------------------------------------------
// Polyline raster (unchanged — verified in round 3).
// ---------------------------------------------------------------------------
__global__ __launch_bounds__(64) void polyline_kernel(const float2* __restrict__ pts, int npts,
                                                      const float* __restrict__ ego, int use_ego,
                                                      float* __restrict__ out_ch) {
    int seg = blockIdx.x;
    if (seg >= npts - 1) return;
    float2 P0 = pts[seg];
    float2 P1 = pts[seg + 1];
    if (use_ego) {
        float yaw = ego[2];
        float cy = cosf(-yaw), sy = sinf(-yaw);
        float ex = ego[0], ey = ego[1];
        float d0x = __fsub_rn(P0.x, ex), d0y = __fsub_rn(P0.y, ey);
        float d1x = __fsub_rn(P1.x, ex), d1y = __fsub_rn(P1.y, ey);
        P0.x = __fsub_rn(__fmul_rn(d0x, cy), __fmul_rn(d0y, sy));
        P0.y = __fadd_rn(__fmul_rn(d0x, sy), __fmul_rn(d0y, cy));
        P1.x = __fsub_rn(__fmul_rn(d1x, cy), __fmul_rn(d1y, sy));
        P1.y = __fadd_rn(__fmul_rn(d1x, sy), __fmul_rn(d1y, cy));
    }
    double ax = trunc(__ddiv_rn(__dadd_rn((double)P0.x, 20.0), 0.1));
    double ay = trunc(__ddiv_rn(__dadd_rn((double)P0.y, 10.0), 0.1));
    double bx = trunc(__ddiv_rn(__dadd_rn((double)P1.x, 20.0), 0.1));
    double by = trunc(__ddiv_rn(__dadd_rn((double)P1.y, 10.0), 0.1));
    bool inA = (ax >= 0.0) && (ax < (double)GW) && (ay >= 0.0) && (ay < (double)GH);
    bool inB = (bx >= 0.0) && (bx < (double)GW) && (by >= 0.0) && (by < (double)GH);
    if (!(inA || inB)) return;
    ax = fmin(fmax(ax, 0.0), (double)(GW - 1));
    ay = fmin(fmax(ay, 0.0), (double)(GH - 1));
    bx = fmin(fmax(bx, 0.0), (double)(GW - 1));
    by = fmin(fmax(by, 0.0), (double)(GH - 1));
    double dx = __dsub_rn(bx, ax);
    double dy = __dsub_rn(by, ay);
    double dmax = fmax(fabs(dx), fabs(dy));
    double denom = fmax(dmax, 1.0);
    int kmax = (int)dmax;
    for (int k = threadIdx.x; k <= kmax; k += blockDim.x) {
        double t = __ddiv_rn(fmin((double)k, dmax), denom);
        double ptx = __dadd_rn(ax, __dmul_rn(t, dx));
        double pty = __dadd_rn(ay, __dmul_rn(t, dy));
        int cx = (int)rint(ptx);
        int cc = (int)rint(pty);
#pragma unroll
        for (int oy = -1; oy <= 1; ++oy) {
#pragma unroll
            for (int ox = -1; ox <= 1; ++ox) {
                int xx = cx + ox;
                int yy = cc + oy;
                if (xx < 0) xx += GW;
                if (yy < 0) yy += GH;
                if (xx >= 0 && xx < GW && yy >= 0 && yy < GH) {
                    out_ch[yy * GW + xx] = 1.0f;
                }
            }
        }
    }
}

extern "C" void kernel_launch(void* const* d_in, const int* in_sizes, int n_in,
                              void* d_out, int out_size, void* d_ws, size_t ws_size,
                              hipStream_t stream) {
    const float* lidar = (const float*)d_in[0];
    const float* traj = (const float*)d_in[1];
    const float* osm = (const float*)d_in[2];
    const float* ego = (const float*)d_in[3];
    float* out = (float*)d_out;

    int n_lidar = in_sizes[0] / 4;
    int n_traj = in_sizes[1] / 2;
    int n_osm = in_sizes[2] / 2;

    // workspace layout
    size_t rec_bytes = (size_t)n_lidar * 8;
    size_t hist_bytes = (size_t)B1 * T_TILES * 4;
    size_t tstart_bytes = (size_t)(T_TILES + 1) * 4;
    size_t need = rec_bytes + hist_bytes + tstart_bytes;

    if (ws_size >= need) {
        unsigned long long* rec = (unsigned long long*)d_ws;
        unsigned* hist = (unsigned*)((char*)d_ws + rec_bytes);
        unsigned* tileStart = (unsigned*)((char*)d_ws + rec_bytes + hist_bytes);
        int per_block = (n_lidar + B1 - 1) / B1;

        init34_kernel<<<(GHW + 255) / 256, 256, 0, stream>>>(out);
        hist_kernel<<<B1, 256, 0, stream>>>((const float4*)lidar, n_lidar, per_block, hist);
        scan_kernel<<<1, 512, 0, stream>>>(hist, tileStart);
        scatter_kernel<<<B1, 256, 0, stream>>>((const float4*)lidar, n_lidar, per_block, hist,
                                               tileStart, rec);
        accum_kernel<<<T_TILES, 256, 0, stream>>>(rec, tileStart, out);
    } else {
        // fallback: verified round-3 atomic path
        init_kernel<<<(GHW + 255) / 256, 256, 0, stream>>>(out);
        lidar_kernel<<<(n_lidar + 255) / 256, 256, 0, stream>>>((const float4*)lidar, n_lidar,
                                                                out);
        finalize_kernel<<<(GHW + 255) / 256, 256, 0, stream>>>(out);
    }

    polyline_kernel<<<n_traj - 1, 64, 0, stream>>>((const float2*)traj, n_traj, nullptr, 0,
                                                   out + 3 * GHW);
    polyline_kernel<<<n_osm - 1, 64, 0, stream>>>((const float2*)osm, n_osm, ego, 1,
                                                  out + 4 * GHW);
}

// Round 5
// 182.261 us; speedup vs baseline: 7.5374x; 1.2236x over previous
//
#include <hip/hip_runtime.h>
#include <math.h>

#define GH 300
#define GW 400
#define GHW (GH * GW)

// Tile grid: 16x16 cells per tile
#define TCOLS 25                 // 400/16
#define TROWS 19                 // ceil(300/16)
#define T_TILES (TCOLS * TROWS)  // 475
#define B1 1024                  // phase-1 blocks: 4 blocks/CU -> 16 waves/CU

// ---------------------------------------------------------------------------
// Shared binning (bit-identical to the verified round-3/4 semantics):
// XLA canonicalization of (x - X0)/RES -> (x + 20) * 10 in f32, no FMA.
// ---------------------------------------------------------------------------
__device__ __forceinline__ bool bin_point(float x, float y, int& px, int& py) {
    if (!(x >= -20.0f && x < 20.0f && y >= -10.0f && y < 30.0f)) return false;
    float qx = __fmul_rn(__fsub_rn(x, -20.0f), 10.0f);
    float qy = __fmul_rn(__fsub_rn(y, -10.0f), 10.0f);
    px = min(max((int)qx, 0), GW - 1);
    py = min(max((int)qy, 0), GH - 1);
    return true;
}

// ---------------------------------------------------------------------------
// Pass A: per-block tile histograms (LDS only; non-atomic global writes).
// hist layout: hist[b * T_TILES + t]  (block-major: hist writes + scatter
// cursor-init reads are coalesced; scanA eats the strided reads, it's tiny).
// ---------------------------------------------------------------------------
__device__ __forceinline__ void hist_one(float4 p, unsigned* cnt) {
    int px, py;
    if (bin_point(p.x, p.y, px, py)) {
        int tile = (py >> 4) * TCOLS + (px >> 4);
        atomicAdd(&cnt[tile], 1u);
    }
}

__global__ __launch_bounds__(256) void hist_kernel(const float4* __restrict__ pts, int n,
                                                   int per_block, unsigned* __restrict__ hist) {
    __shared__ unsigned cnt[T_TILES];
    for (int t = threadIdx.x; t < T_TILES; t += 256) cnt[t] = 0;
    __syncthreads();
    int start = blockIdx.x * per_block;
    int end = min(start + per_block, n);
    int i = start + (int)threadIdx.x;
    // 4x unroll: 4 independent loads in flight
    for (; i + 768 < end; i += 1024) {
        float4 p0 = pts[i];
        float4 p1 = pts[i + 256];
        float4 p2 = pts[i + 512];
        float4 p3 = pts[i + 768];
        hist_one(p0, cnt);
        hist_one(p1, cnt);
        hist_one(p2, cnt);
        hist_one(p3, cnt);
    }
    for (; i < end; i += 256) hist_one(pts[i], cnt);
    __syncthreads();
    for (int t = threadIdx.x; t < T_TILES; t += 256)
        hist[blockIdx.x * T_TILES + t] = cnt[t];
}

// ---------------------------------------------------------------------------
// scanA: one wave per tile. Exclusive prefix over the B1 per-block counts
// (16 chunks of 64, shfl_up wave scan). Writes back in place + tile totals.
// ---------------------------------------------------------------------------
__global__ __launch_bounds__(64) void scanA_kernel(unsigned* __restrict__ hist,
                                                   unsigned* __restrict__ tileTot) {
    int t = blockIdx.x;
    int lane = threadIdx.x;
    unsigned run = 0;
    for (int c = 0; c < B1; c += 64) {
        unsigned v = hist[(c + lane) * T_TILES + t];
        unsigned orig = v;
#pragma unroll
        for (int d = 1; d < 64; d <<= 1) {
            unsigned u = __shfl_up(v, d, 64);
            if (lane >= d) v += u;
        }
        hist[(c + lane) * T_TILES + t] = run + (v - orig);  // exclusive
        run += __shfl(v, 63, 64);
    }
    if (lane == 0) tileTot[t] = run;
}

// ---------------------------------------------------------------------------
// scanB: single block, Hillis-Steele over the 475 tile totals -> tileStart.
// ---------------------------------------------------------------------------
__global__ __launch_bounds__(512) void scanB_kernel(const unsigned* __restrict__ tileTot,
                                                    unsigned* __restrict__ tileStart) {
    __shared__ unsigned s[512];
    int i = threadIdx.x;
    s[i] = (i < T_TILES) ? tileTot[i] : 0u;
    __syncthreads();
    for (int d = 1; d < 512; d <<= 1) {
        unsigned v = (i >= d) ? s[i - d] : 0u;
        __syncthreads();
        s[i] += v;
        __syncthreads();
    }
    if (i == 0) tileStart[0] = 0u;
    if (i < T_TILES) tileStart[i + 1] = s[i];  // inclusive -> start of next
}

// ---------------------------------------------------------------------------
// Pass B: scatter packed records into tile-sorted order. LDS cursors give
// unique slots (no global atomics). Record: [z16 | i16 | local8] in a u64.
//   z16 = round((z+3)*65535/7) clamped  (h tol 2e-2 >> 1.5e-5 quant err)
//   i16 = round(inten*256) clamped      (8.8 fixed; i tol >> quant err)
// ---------------------------------------------------------------------------
__device__ __forceinline__ void scatter_one(float4 p, unsigned* cur,
                                            unsigned long long* __restrict__ rec) {
    int px, py;
    if (bin_point(p.x, p.y, px, py)) {
        int tile = (py >> 4) * TCOLS + (px >> 4);
        int local = ((py & 15) << 4) | (px & 15);
        int z16 = (int)rintf(__fmul_rn(__fsub_rn(p.z, -3.0f), 65535.0f / 7.0f));
        z16 = min(max(z16, 0), 65535);
        int i16 = (int)rintf(__fmul_rn(p.w, 256.0f));
        i16 = min(max(i16, 0), 65535);
        unsigned pos = atomicAdd(&cur[tile], 1u);
        rec[pos] = ((unsigned long long)(unsigned)z16 << 32) |
                   ((unsigned long long)(unsigned)i16 << 16) | (unsigned)local;
    }
}

__global__ __launch_bounds__(256) void scatter_kernel(const float4* __restrict__ pts, int n,
                                                      int per_block,
                                                      const unsigned* __restrict__ hist,
                                                      const unsigned* __restrict__ tileStart,
                                                      unsigned long long* __restrict__ rec) {
    __shared__ unsigned cur[T_TILES];
    for (int t = threadIdx.x; t < T_TILES; t += 256)
        cur[t] = tileStart[t] + hist[blockIdx.x * T_TILES + t];
    __syncthreads();
    int start = blockIdx.x * per_block;
    int end = min(start + per_block, n);
    int i = start + (int)threadIdx.x;
    for (; i + 768 < end; i += 1024) {
        float4 p0 = pts[i];
        float4 p1 = pts[i + 256];
        float4 p2 = pts[i + 512];
        float4 p3 = pts[i + 768];
        scatter_one(p0, cur, rec);
        scatter_one(p1, cur, rec);
        scatter_one(p2, cur, rec);
        scatter_one(p3, cur, rec);
    }
    for (; i < end; i += 256) scatter_one(pts[i], cur, rec);
}

// ---------------------------------------------------------------------------
// Accumulate per tile in LDS, finalize h/i/d, store (no atomics beyond LDS).
// ic packs (cnt << 40) | sum_i16 — overflow impossible: 4e6*65280 < 2^40.
// ---------------------------------------------------------------------------
__global__ __launch_bounds__(256) void accum_kernel(const unsigned long long* __restrict__ rec,
                                                    const unsigned* __restrict__ tileStart,
                                                    float* __restrict__ out) {
    __shared__ unsigned zmax[256];          // 0 = empty; else z16+1
    __shared__ unsigned long long ic[256];  // (cnt<<40) | sum_i16
    zmax[threadIdx.x] = 0;
    ic[threadIdx.x] = 0;
    __syncthreads();
    unsigned s = tileStart[blockIdx.x];
    unsigned e = tileStart[blockIdx.x + 1];
    for (unsigned i = s + threadIdx.x; i < e; i += 256) {
        unsigned long long r = rec[i];
        int local = (int)(r & 0xFF);
        unsigned z16 = (unsigned)(r >> 32) & 0xFFFFu;
        unsigned long long i16 = (r >> 16) & 0xFFFFull;
        atomicMax(&zmax[local], z16 + 1u);
        atomicAdd(&ic[local], (1ull << 40) | i16);
    }
    __syncthreads();
    int l = threadIdx.x;
    int trow = blockIdx.x / TCOLS, tcol = blockIdx.x % TCOLS;
    int gy = trow * 16 + (l >> 4);
    int gx = tcol * 16 + (l & 15);
    if (gy < GH) {
        const float inv7 = 1.0f / 7.0f;
        const float invlog129 = 1.0f / 4.8598124043616719e+00f;  // 1/log(129)
        unsigned long long v = ic[l];
        float h, ich, dd;
        if (v == 0) {
            h = fminf(fmaxf(__fmul_rn(3.0f, inv7), 0.0f), 1.0f);  // empty: clip(3/7)
            ich = 0.0f;
            dd = 0.0f;
        } else {
            unsigned cnt = (unsigned)(v >> 40);
            float sum16 = (float)(v & ((1ull << 40) - 1));  // sum of inten*256
            h = fminf((float)(zmax[l] - 1u) * (1.0f / 65535.0f), 1.0f);
            ich = fminf(__fdiv_rn(sum16, __fmul_rn((float)cnt, 65280.0f)), 1.0f);
            dd = fminf(__fmul_rn(log1pf((float)cnt), invlog129), 1.0f);
        }
        int idx = gy * GW + gx;
        out[0 * GHW + idx] = h;
        out[1 * GHW + idx] = ich;
        out[2 * GHW + idx] = dd;
    }
}

// ---------------------------------------------------------------------------
// Zero only the polyline channels (accum writes ch0..2 fully).
// ---------------------------------------------------------------------------
__global__ __launch_bounds__(256) void init34_kernel(float* __restrict__ out) {
    int i = blockIdx.x * blockDim.x + threadIdx.x;
    if (i < GHW) {
        out[3 * GHW + i] = 0.0f;
        out[4 * GHW + i] = 0.0f;
    }
}

// ---------------------------------------------------------------------------
// Both polylines in one launch. Math byte-identical to the verified R3 path.
// Blocks [0, ntraj-1) -> trajectory/ch3; rest -> osm/ch4 (ego rotation).
// ---------------------------------------------------------------------------
__global__ __launch_bounds__(64) void polylines_kernel(const float2* __restrict__ traj, int ntraj,
                                                       const float2* __restrict__ osm, int nosm,
                                                       const float* __restrict__ ego,
                                                       float* __restrict__ out) {
    int s = blockIdx.x;
    const float2* pts;
    float* out_ch;
    bool use_ego;
    if (s < ntraj - 1) {
        pts = traj + s;
        out_ch = out + 3 * GHW;
        use_ego = false;
    } else {
        s -= (ntraj - 1);
        if (s >= nosm - 1) return;
        pts = osm + s;
        out_ch = out + 4 * GHW;
        use_ego = true;
    }
    float2 P0 = pts[0];
    float2 P1 = pts[1];
    if (use_ego) {
        float yaw = ego[2];
        float cy = cosf(-yaw), sy = sinf(-yaw);
        float ex = ego[0], ey = ego[1];
        float d0x = __fsub_rn(P0.x, ex), d0y = __fsub_rn(P0.y, ey);
        float d1x = __fsub_rn(P1.x, ex), d1y = __fsub_rn(P1.y, ey);
        P0.x = __fsub_rn(__fmul_rn(d0x, cy), __fmul_rn(d0y, sy));
        P0.y = __fadd_rn(__fmul_rn(d0x, sy), __fmul_rn(d0y, cy));
        P1.x = __fsub_rn(__fmul_rn(d1x, cy), __fmul_rn(d1y, sy));
        P1.y = __fadd_rn(__fmul_rn(d1x, sy), __fmul_rn(d1y, cy));
    }
    double ax = trunc(__ddiv_rn(__dadd_rn((double)P0.x, 20.0), 0.1));
    double ay = trunc(__ddiv_rn(__dadd_rn((double)P0.y, 10.0), 0.1));
    double bx = trunc(__ddiv_rn(__dadd_rn((double)P1.x, 20.0), 0.1));
    double by = trunc(__ddiv_rn(__dadd_rn((double)P1.y, 10.0), 0.1));
    bool inA = (ax >= 0.0) && (ax < (double)GW) && (ay >= 0.0) && (ay < (double)GH);
    bool inB = (bx >= 0.0) && (bx < (double)GW) && (by >= 0.0) && (by < (double)GH);
    if (!(inA || inB)) return;
    ax = fmin(fmax(ax, 0.0), (double)(GW - 1));
    ay = fmin(fmax(ay, 0.0), (double)(GH - 1));
    bx = fmin(fmax(bx, 0.0), (double)(GW - 1));
    by = fmin(fmax(by, 0.0), (double)(GH - 1));
    double dx = __dsub_rn(bx, ax);
    double dy = __dsub_rn(by, ay);
    double dmax = fmax(fabs(dx), fabs(dy));
    double denom = fmax(dmax, 1.0);
    int kmax = (int)dmax;
    for (int k = threadIdx.x; k <= kmax; k += blockDim.x) {
        double t = __ddiv_rn(fmin((double)k, dmax), denom);
        double ptx = __dadd_rn(ax, __dmul_rn(t, dx));
        double pty = __dadd_rn(ay, __dmul_rn(t, dy));
        int cx = (int)rint(ptx);  // half-to-even
        int cc = (int)rint(pty);
#pragma unroll
        for (int oy = -1; oy <= 1; ++oy) {
#pragma unroll
            for (int ox = -1; ox <= 1; ++ox) {
                int xx = cx + ox;
                int yy = cc + oy;
                if (xx < 0) xx += GW;  // JAX wraps negatives, drops OOB
                if (yy < 0) yy += GH;
                if (xx >= 0 && xx < GW && yy >= 0 && yy < GH) {
                    out_ch[yy * GW + xx] = 1.0f;
                }
            }
        }
    }
}

// ======================== fallback (round-3) path ==========================
__global__ __launch_bounds__(256) void init_kernel(float* __restrict__ out) {
    int i = blockIdx.x * blockDim.x + threadIdx.x;
    if (i < GHW) {
        out[0 * GHW + i] = -INFINITY;
        out[1 * GHW + i] = 0.0f;
        out[2 * GHW + i] = 0.0f;
        out[3 * GHW + i] = 0.0f;
        out[4 * GHW + i] = 0.0f;
    }
}

__device__ __forceinline__ void atomicMaxFloat(float* addr, float val) {
    if (val >= 0.0f) {
        atomicMax((int*)addr, __float_as_int(val));
    } else {
        atomicMin((unsigned int*)addr, (unsigned int)__float_as_int(val));
    }
}

__global__ __launch_bounds__(256) void lidar_kernel(const float4* __restrict__ pts, int n,
                                                    float* __restrict__ out) {
    int i = blockIdx.x * blockDim.x + threadIdx.x;
    if (i >= n) return;
    float4 p = pts[i];
    int px, py;
    if (!bin_point(p.x, p.y, px, py)) return;
    int idx = py * GW + px;
    atomicMaxFloat(&out[0 * GHW + idx], p.z);
    atomicAdd(&out[1 * GHW + idx], p.w);
    atomicAdd(&out[2 * GHW + idx], 1.0f);
}

__global__ __launch_bounds__(256) void finalize_kernel(float* __restrict__ out) {
    int i = blockIdx.x * blockDim.x + threadIdx.x;
    if (i >= GHW) return;
    float hm = out[0 * GHW + i];
    float isum = out[1 * GHW + i];
    float c = out[2 * GHW + i];
    if (hm == -INFINITY) hm = 0.0f;
    const float inv7 = 1.0f / 7.0f;
    const float inv255 = 1.0f / 255.0f;
    const float invlog129 = 1.0f / 4.8598124043616719e+00f;
    float h = fminf(fmaxf(__fmul_rn(__fadd_rn(hm, 3.0f), inv7), 0.0f), 1.0f);
    float im = (c > 0.0f) ? __fdiv_rn(isum, fmaxf(c, 1.0f)) : 0.0f;
    float ich = fminf(fmaxf(__fmul_rn(im, inv255), 0.0f), 1.0f);
    float dd = fminf(fmaxf(__fmul_rn(log1pf(c), invlog129), 0.0f), 1.0f);
    out[0 * GHW + i] = h;
    out[1 * GHW + i] = ich;
    out[2 * GHW + i] = dd;
}

extern "C" void kernel_launch(void* const* d_in, const int* in_sizes, int n_in,
                              void* d_out, int out_size, void* d_ws, size_t ws_size,
                              hipStream_t stream) {
    const float* lidar = (const float*)d_in[0];
    const float* traj = (const float*)d_in[1];
    const float* osm = (const float*)d_in[2];
    const float* ego = (const float*)d_in[3];
    float* out = (float*)d_out;

    int n_lidar = in_sizes[0] / 4;
    int n_traj = in_sizes[1] / 2;
    int n_osm = in_sizes[2] / 2;

    // workspace layout
    size_t rec_bytes = (size_t)n_lidar * 8;
    size_t hist_bytes = (size_t)B1 * T_TILES * 4;
    size_t ttot_bytes = (size_t)T_TILES * 4;
    size_t tstart_bytes = (size_t)(T_TILES + 1) * 4;
    size_t need = rec_bytes + hist_bytes + ttot_bytes + tstart_bytes;

    if (ws_size >= need) {
        char* w = (char*)d_ws;
        unsigned long long* rec = (unsigned long long*)w;
        unsigned* hist = (unsigned*)(w + rec_bytes);
        unsigned* tileTot = (unsigned*)(w + rec_bytes + hist_bytes);
        unsigned* tileStart = (unsigned*)(w + rec_bytes + hist_bytes + ttot_bytes);
        int per_block = (n_lidar + B1 - 1) / B1;

        init34_kernel<<<(GHW + 255) / 256, 256, 0, stream>>>(out);
        hist_kernel<<<B1, 256, 0, stream>>>((const float4*)lidar, n_lidar, per_block, hist);
        scanA_kernel<<<T_TILES, 64, 0, stream>>>(hist, tileTot);
        scanB_kernel<<<1, 512, 0, stream>>>(tileTot, tileStart);
        scatter_kernel<<<B1, 256, 0, stream>>>((const float4*)lidar, n_lidar, per_block, hist,
                                               tileStart, rec);
        accum_kernel<<<T_TILES, 256, 0, stream>>>(rec, tileStart, out);
    } else {
        // fallback: verified round-3 atomic path
        init_kernel<<<(GHW + 255) / 256, 256, 0, stream>>>(out);
        lidar_kernel<<<(n_lidar + 255) / 256, 256, 0, stream>>>((const float4*)lidar, n_lidar,
                                                                out);
        finalize_kernel<<<(GHW + 255) / 256, 256, 0, stream>>>(out);
    }

    int nseg = (n_traj - 1) + (n_osm - 1);
    polylines_kernel<<<nseg, 64, 0, stream>>>((const float2*)traj, n_traj, (const float2*)osm,
                                              n_osm, ego, out);
}

// Round 6
// 169.679 us; speedup vs baseline: 8.0963x; 1.0742x over previous
//
#include <hip/hip_runtime.h>
#include <math.h>

#define GH 300
#define GW 400
#define GHW (GH * GW)

// Tile grid: 16x16 cells per tile
#define TCOLS 25                 // 400/16
#define TROWS 19                 // ceil(300/16)
#define T_TILES (TCOLS * TROWS)  // 475
#define B1 256                   // phase-1 blocks (ILP-deep, not TLP-deep)

// ---------------------------------------------------------------------------
// Shared binning (bit-identical to the verified round-3/4/5 semantics):
// XLA canonicalization of (x - X0)/RES -> (x + 20) * 10 in f32, no FMA.
// ---------------------------------------------------------------------------
__device__ __forceinline__ bool bin_point(float x, float y, int& px, int& py) {
    if (!(x >= -20.0f && x < 20.0f && y >= -10.0f && y < 30.0f)) return false;
    float qx = __fmul_rn(__fsub_rn(x, -20.0f), 10.0f);
    float qy = __fmul_rn(__fsub_rn(y, -10.0f), 10.0f);
    px = min(max((int)qx, 0), GW - 1);
    py = min(max((int)qy, 0), GH - 1);
    return true;
}

// Wave-0 exclusive scan of tileTot[0..T_TILES) into LDS tileStart_s[0..T_TILES].
// Caller must __syncthreads() afterwards.
__device__ __forceinline__ void tile_prefix_wave0(const unsigned* __restrict__ tileTot,
                                                  unsigned* tileStart_s) {
    int lane = threadIdx.x;
    if (lane < 64) {
        unsigned run = 0;
        for (int c = 0; c < T_TILES; c += 64) {
            int idx = c + lane;
            unsigned v = (idx < T_TILES) ? tileTot[idx] : 0u;
            unsigned orig = v;
#pragma unroll
            for (int d = 1; d < 64; d <<= 1) {
                unsigned u = __shfl_up(v, d, 64);
                if (lane >= d) v += u;
            }
            if (idx < T_TILES) tileStart_s[idx] = run + (v - orig);  // exclusive
            run += __shfl(v, 63, 64);
        }
        if (lane == 0) tileStart_s[T_TILES] = run;
    }
}

// ---------------------------------------------------------------------------
// Pass A: per-block tile histograms (LDS only). Also zeros polyline channels
// ch3/ch4 (safe: polyline stamps run in a later stream-ordered kernel).
// hist layout: hist[b * T_TILES + t] (coalesced writes + scatter reads).
// ---------------------------------------------------------------------------
__device__ __forceinline__ void hist_one(float4 p, unsigned* cnt) {
    int px, py;
    if (bin_point(p.x, p.y, px, py)) {
        int tile = (py >> 4) * TCOLS + (px >> 4);
        atomicAdd(&cnt[tile], 1u);
    }
}

__global__ __launch_bounds__(256) void hist_kernel(const float4* __restrict__ pts, int n,
                                                   int per_block, unsigned* __restrict__ hist,
                                                   float* __restrict__ out) {
    __shared__ unsigned cnt[T_TILES];
    for (int t = threadIdx.x; t < T_TILES; t += 256) cnt[t] = 0;
    // zero ch3/ch4: 2*GHW floats = 60000 float4 (16B-aligned: 3*GHW*4 % 16 == 0)
    float4* z4 = (float4*)(out + 3 * GHW);
    for (int j = blockIdx.x * 256 + (int)threadIdx.x; j < (2 * GHW) / 4; j += B1 * 256)
        z4[j] = make_float4(0.0f, 0.0f, 0.0f, 0.0f);
    __syncthreads();
    int start = blockIdx.x * per_block;
    int end = min(start + per_block, n);
    int i = start + (int)threadIdx.x;
    // 8x unroll: 8 independent 16B loads in flight per thread (32 KB/CU)
    for (; i + 7 * 256 < end; i += 8 * 256) {
        float4 p[8];
#pragma unroll
        for (int j = 0; j < 8; ++j) p[j] = pts[i + j * 256];
#pragma unroll
        for (int j = 0; j < 8; ++j) hist_one(p[j], cnt);
    }
    for (; i < end; i += 256) hist_one(pts[i], cnt);
    __syncthreads();
    for (int t = threadIdx.x; t < T_TILES; t += 256)
        hist[blockIdx.x * T_TILES + t] = cnt[t];
}

// ---------------------------------------------------------------------------
// scanA: one wave per tile. Exclusive prefix over the B1 per-block counts
// (4 chunks of 64, shfl_up wave scan). Writes back in place + tile totals.
// ---------------------------------------------------------------------------
__global__ __launch_bounds__(64) void scanA_kernel(unsigned* __restrict__ hist,
                                                   unsigned* __restrict__ tileTot) {
    int t = blockIdx.x;
    int lane = threadIdx.x;
    unsigned run = 0;
    for (int c = 0; c < B1; c += 64) {
        unsigned v = hist[(c + lane) * T_TILES + t];
        unsigned orig = v;
#pragma unroll
        for (int d = 1; d < 64; d <<= 1) {
            unsigned u = __shfl_up(v, d, 64);
            if (lane >= d) v += u;
        }
        hist[(c + lane) * T_TILES + t] = run + (v - orig);  // exclusive
        run += __shfl(v, 63, 64);
    }
    if (lane == 0) tileTot[t] = run;
}

// ---------------------------------------------------------------------------
// Pass B: scatter packed records into tile-sorted order. LDS cursors give
// unique slots (no global atomics). Record: [key32 | i16 | 8b pad-free local]:
//   key32 = f32 bits of fadd(z, 3.0f)  (monotone in z, >= 0; EXACT h later:
//           reference computes h = clip(fmul(fadd(hmax,3),1/7)) — same value)
//   i16   = round(inten*256) clamped   (8.8 fixed; exact integer summation)
// ---------------------------------------------------------------------------
__device__ __forceinline__ void scatter_one(float4 p, unsigned* cur,
                                            unsigned long long* __restrict__ rec) {
    int px, py;
    if (bin_point(p.x, p.y, px, py)) {
        int tile = (py >> 4) * TCOLS + (px >> 4);
        int local = ((py & 15) << 4) | (px & 15);
        unsigned key = __float_as_uint(__fadd_rn(p.z, 3.0f));  // z>=-3 -> key>=0
        int i16 = min(max((int)rintf(__fmul_rn(p.w, 256.0f)), 0), 65535);
        unsigned pos = atomicAdd(&cur[tile], 1u);
        rec[pos] = ((unsigned long long)key << 32) |
                   ((unsigned long long)(unsigned)i16 << 16) | (unsigned)local;
    }
}

__global__ __launch_bounds__(256) void scatter_kernel(const float4* __restrict__ pts, int n,
                                                      int per_block,
                                                      const unsigned* __restrict__ hist,
                                                      const unsigned* __restrict__ tileTot,
                                                      unsigned long long* __restrict__ rec) {
    __shared__ unsigned tileStart_s[T_TILES + 1];
    __shared__ unsigned cur[T_TILES];
    tile_prefix_wave0(tileTot, tileStart_s);
    __syncthreads();
    for (int t = threadIdx.x; t < T_TILES; t += 256)
        cur[t] = tileStart_s[t] + hist[blockIdx.x * T_TILES + t];
    __syncthreads();
    int start = blockIdx.x * per_block;
    int end = min(start + per_block, n);
    int i = start + (int)threadIdx.x;
    for (; i + 7 * 256 < end; i += 8 * 256) {
        float4 p[8];
#pragma unroll
        for (int j = 0; j < 8; ++j) p[j] = pts[i + j * 256];
#pragma unroll
        for (int j = 0; j < 8; ++j) scatter_one(p[j], cur, rec);
    }
    for (; i < end; i += 256) scatter_one(pts[i], cur, rec);
}

// ---------------------------------------------------------------------------
// Polyline segment rasterizer, thread-per-segment (math byte-identical to the
// verified R3/R5 path; looping k serially covers the same sample set).
// ---------------------------------------------------------------------------
__device__ void do_poly_segment(int seg, const float2* __restrict__ traj, int ntraj,
                                const float2* __restrict__ osm, int nosm,
                                const float* __restrict__ ego, float* __restrict__ out) {
    int ntseg = ntraj - 1;
    int noseg = nosm - 1;
    if (seg >= ntseg + noseg) return;
    const float2* pts;
    float* out_ch;
    bool use_ego;
    if (seg < ntseg) {
        pts = traj + seg;
        out_ch = out + 3 * GHW;
        use_ego = false;
    } else {
        pts = osm + (seg - ntseg);
        out_ch = out + 4 * GHW;
        use_ego = true;
    }
    float2 P0 = pts[0];
    float2 P1 = pts[1];
    if (use_ego) {
        float yaw = ego[2];
        float cy = cosf(-yaw), sy = sinf(-yaw);
        float ex = ego[0], ey = ego[1];
        float d0x = __fsub_rn(P0.x, ex), d0y = __fsub_rn(P0.y, ey);
        float d1x = __fsub_rn(P1.x, ex), d1y = __fsub_rn(P1.y, ey);
        P0.x = __fsub_rn(__fmul_rn(d0x, cy), __fmul_rn(d0y, sy));
        P0.y = __fadd_rn(__fmul_rn(d0x, sy), __fmul_rn(d0y, cy));
        P1.x = __fsub_rn(__fmul_rn(d1x, cy), __fmul_rn(d1y, sy));
        P1.y = __fadd_rn(__fmul_rn(d1x, sy), __fmul_rn(d1y, cy));
    }
    double ax = trunc(__ddiv_rn(__dadd_rn((double)P0.x, 20.0), 0.1));
    double ay = trunc(__ddiv_rn(__dadd_rn((double)P0.y, 10.0), 0.1));
    double bx = trunc(__ddiv_rn(__dadd_rn((double)P1.x, 20.0), 0.1));
    double by = trunc(__ddiv_rn(__dadd_rn((double)P1.y, 10.0), 0.1));
    bool inA = (ax >= 0.0) && (ax < (double)GW) && (ay >= 0.0) && (ay < (double)GH);
    bool inB = (bx >= 0.0) && (bx < (double)GW) && (by >= 0.0) && (by < (double)GH);
    if (!(inA || inB)) return;
    ax = fmin(fmax(ax, 0.0), (double)(GW - 1));
    ay = fmin(fmax(ay, 0.0), (double)(GH - 1));
    bx = fmin(fmax(bx, 0.0), (double)(GW - 1));
    by = fmin(fmax(by, 0.0), (double)(GH - 1));
    double dx = __dsub_rn(bx, ax);
    double dy = __dsub_rn(by, ay);
    double dmax = fmax(fabs(dx), fabs(dy));
    double denom = fmax(dmax, 1.0);
    int kmax = (int)dmax;
    for (int k = 0; k <= kmax; ++k) {
        double t = __ddiv_rn(fmin((double)k, dmax), denom);
        double ptx = __dadd_rn(ax, __dmul_rn(t, dx));
        double pty = __dadd_rn(ay, __dmul_rn(t, dy));
        int cx = (int)rint(ptx);  // half-to-even
        int cc = (int)rint(pty);
#pragma unroll
        for (int oy = -1; oy <= 1; ++oy) {
#pragma unroll
            for (int ox = -1; ox <= 1; ++ox) {
                int xx = cx + ox;
                int yy = cc + oy;
                if (xx < 0) xx += GW;  // JAX wraps negatives, drops OOB
                if (yy < 0) yy += GH;
                if (xx >= 0 && xx < GW && yy >= 0 && yy < GH) {
                    out_ch[yy * GW + xx] = 1.0f;
                }
            }
        }
    }
}

// ---------------------------------------------------------------------------
// Merged epilogue: blocks [0, T_TILES) accumulate+finalize lidar channels;
// blocks [T_TILES, ...) rasterize polyline segments (thread-per-segment).
// ic packs (cnt << 40) | sum_i16 — overflow impossible: 4e6*65280 < 2^40.
// ---------------------------------------------------------------------------
__global__ __launch_bounds__(256) void accum_poly_kernel(
    const unsigned long long* __restrict__ rec, const unsigned* __restrict__ tileTot,
    float* __restrict__ out, const float2* __restrict__ traj, int ntraj,
    const float2* __restrict__ osm, int nosm, const float* __restrict__ ego) {
    if (blockIdx.x >= T_TILES) {
        int seg = (blockIdx.x - T_TILES) * 256 + (int)threadIdx.x;
        do_poly_segment(seg, traj, ntraj, osm, nosm, ego, out);
        return;
    }
    __shared__ unsigned tileStart_s[T_TILES + 1];
    __shared__ unsigned zmax[256];          // f32 bits of (z+3), all >= 0
    __shared__ unsigned long long ic[256];  // (cnt<<40) | sum_i16
    tile_prefix_wave0(tileTot, tileStart_s);
    zmax[threadIdx.x] = 0;
    ic[threadIdx.x] = 0;
    __syncthreads();
    unsigned s = tileStart_s[blockIdx.x];
    unsigned e = tileStart_s[blockIdx.x + 1];
    for (unsigned i = s + threadIdx.x; i < e; i += 256) {
        unsigned long long r = rec[i];
        int local = (int)(r & 0xFF);
        unsigned key = (unsigned)(r >> 32);
        unsigned long long i16 = (r >> 16) & 0xFFFFull;
        atomicMax(&zmax[local], key);
        atomicAdd(&ic[local], (1ull << 40) | i16);
    }
    __syncthreads();
    int l = threadIdx.x;
    int trow = blockIdx.x / TCOLS, tcol = blockIdx.x % TCOLS;
    int gy = trow * 16 + (l >> 4);
    int gx = tcol * 16 + (l & 15);
    if (gy < GH) {
        const float inv7 = 1.0f / 7.0f;
        const float invlog129 = 1.0f / 4.8598124043616719e+00f;  // 1/log(129)
        unsigned long long v = ic[l];
        float h, ich, dd;
        if (v == 0) {
            h = fminf(fmaxf(__fmul_rn(3.0f, inv7), 0.0f), 1.0f);  // empty: clip(3/7)
            ich = 0.0f;
            dd = 0.0f;
        } else {
            unsigned cnt = (unsigned)(v >> 40);
            float sum16 = (float)(v & ((1ull << 40) - 1));       // sum of inten*256
            float keyf = __uint_as_float(zmax[l]);               // = fadd(hmax, 3.0f) exactly
            h = fminf(fmaxf(__fmul_rn(keyf, inv7), 0.0f), 1.0f); // exact reference h
            ich = fminf(__fdiv_rn(sum16, __fmul_rn((float)cnt, 65280.0f)), 1.0f);
            dd = fminf(__fmul_rn(log1pf((float)cnt), invlog129), 1.0f);
        }
        int idx = gy * GW + gx;
        out[0 * GHW + idx] = h;
        out[1 * GHW + idx] = ich;
        out[2 * GHW + idx] = dd;
    }
}

// Standalone polyline kernel (fallback path).
__global__ __launch_bounds__(256) void polylines_kernel(const float2* __restrict__ traj,
                                                        int ntraj,
                                                        const float2* __restrict__ osm, int nosm,
                                                        const float* __restrict__ ego,
                                                        float* __restrict__ out) {
    int seg = blockIdx.x * 256 + (int)threadIdx.x;
    do_poly_segment(seg, traj, ntraj, osm, nosm, ego, out);
}

// ======================== fallback (round-3) path ==========================
__global__ __launch_bounds__(256) void init_kernel(float* __restrict__ out) {
    int i = blockIdx.x * blockDim.x + threadIdx.x;
    if (i < GHW) {
        out[0 * GHW + i] = -INFINITY;
        out[1 * GHW + i] = 0.0f;
        out[2 * GHW + i] = 0.0f;
        out[3 * GHW + i] = 0.0f;
        out[4 * GHW + i] = 0.0f;
    }
}

__device__ __forceinline__ void atomicMaxFloat(float* addr, float val) {
    if (val >= 0.0f) {
        atomicMax((int*)addr, __float_as_int(val));
    } else {
        atomicMin((unsigned int*)addr, (unsigned int)__float_as_int(val));
    }
}

__global__ __launch_bounds__(256) void lidar_kernel(const float4* __restrict__ pts, int n,
                                                    float* __restrict__ out) {
    int i = blockIdx.x * blockDim.x + threadIdx.x;
    if (i >= n) return;
    float4 p = pts[i];
    int px, py;
    if (!bin_point(p.x, p.y, px, py)) return;
    int idx = py * GW + px;
    atomicMaxFloat(&out[0 * GHW + idx], p.z);
    atomicAdd(&out[1 * GHW + idx], p.w);
    atomicAdd(&out[2 * GHW + idx], 1.0f);
}

__global__ __launch_bounds__(256) void finalize_kernel(float* __restrict__ out) {
    int i = blockIdx.x * blockDim.x + threadIdx.x;
    if (i >= GHW) return;
    float hm = out[0 * GHW + i];
    float isum = out[1 * GHW + i];
    float c = out[2 * GHW + i];
    if (hm == -INFINITY) hm = 0.0f;
    const float inv7 = 1.0f / 7.0f;
    const float inv255 = 1.0f / 255.0f;
    const float invlog129 = 1.0f / 4.8598124043616719e+00f;
    float h = fminf(fmaxf(__fmul_rn(__fadd_rn(hm, 3.0f), inv7), 0.0f), 1.0f);
    float im = (c > 0.0f) ? __fdiv_rn(isum, fmaxf(c, 1.0f)) : 0.0f;
    float ich = fminf(fmaxf(__fmul_rn(im, inv255), 0.0f), 1.0f);
    float dd = fminf(fmaxf(__fmul_rn(log1pf(c), invlog129), 0.0f), 1.0f);
    out[0 * GHW + i] = h;
    out[1 * GHW + i] = ich;
    out[2 * GHW + i] = dd;
}

extern "C" void kernel_launch(void* const* d_in, const int* in_sizes, int n_in,
                              void* d_out, int out_size, void* d_ws, size_t ws_size,
                              hipStream_t stream) {
    const float* lidar = (const float*)d_in[0];
    const float* traj = (const float*)d_in[1];
    const float* osm = (const float*)d_in[2];
    const float* ego = (const float*)d_in[3];
    float* out = (float*)d_out;

    int n_lidar = in_sizes[0] / 4;
    int n_traj = in_sizes[1] / 2;
    int n_osm = in_sizes[2] / 2;
    int nseg = (n_traj - 1) + (n_osm - 1);

    // workspace layout
    size_t rec_bytes = (size_t)n_lidar * 8;
    size_t hist_bytes = (size_t)B1 * T_TILES * 4;
    size_t ttot_bytes = (size_t)T_TILES * 4;
    size_t need = rec_bytes + hist_bytes + ttot_bytes;

    if (ws_size >= need) {
        char* w = (char*)d_ws;
        unsigned long long* rec = (unsigned long long*)w;
        unsigned* hist = (unsigned*)(w + rec_bytes);
        unsigned* tileTot = (unsigned*)(w + rec_bytes + hist_bytes);
        int per_block = (n_lidar + B1 - 1) / B1;
        int npb = (nseg + 255) / 256;

        hist_kernel<<<B1, 256, 0, stream>>>((const float4*)lidar, n_lidar, per_block, hist, out);
        scanA_kernel<<<T_TILES, 64, 0, stream>>>(hist, tileTot);
        scatter_kernel<<<B1, 256, 0, stream>>>((const float4*)lidar, n_lidar, per_block, hist,
                                               tileTot, rec);
        accum_poly_kernel<<<T_TILES + npb, 256, 0, stream>>>(rec, tileTot, out,
                                                             (const float2*)traj, n_traj,
                                                             (const float2*)osm, n_osm, ego);
    } else {
        // fallback: verified round-3 atomic path
        init_kernel<<<(GHW + 255) / 256, 256, 0, stream>>>(out);
        lidar_kernel<<<(n_lidar + 255) / 256, 256, 0, stream>>>((const float4*)lidar, n_lidar,
                                                                out);
        finalize_kernel<<<(GHW + 255) / 256, 256, 0, stream>>>(out);
        polylines_kernel<<<(nseg + 255) / 256, 256, 0, stream>>>((const float2*)traj, n_traj,
                                                                 (const float2*)osm, n_osm, ego,
                                                                 out);
    }
}

// Round 7
// 166.258 us; speedup vs baseline: 8.2629x; 1.0206x over previous
//
#include <hip/hip_runtime.h>
#include <math.h>

#define GH 300
#define GW 400
#define GHW (GH * GW)

// Tile grid: 16x16 cells per tile
#define TCOLS 25                 // 400/16
#define TROWS 19                 // ceil(300/16)
#define T_TILES (TCOLS * TROWS)  // 475
#define B1 512                   // P1 blocks
#define Q 32                     // per-thread LDS record quota (per_block <= 8192)

// ---------------------------------------------------------------------------
// Shared binning (bit-identical to the verified round-3..6 semantics):
// XLA canonicalization of (x - X0)/RES -> (x + 20) * 10 in f32, no FMA.
// ---------------------------------------------------------------------------
__device__ __forceinline__ bool bin_point(float x, float y, int& px, int& py) {
    if (!(x >= -20.0f && x < 20.0f && y >= -10.0f && y < 30.0f)) return false;
    float qx = __fmul_rn(__fsub_rn(x, -20.0f), 10.0f);
    float qy = __fmul_rn(__fsub_rn(y, -10.0f), 10.0f);
    px = min(max((int)qx, 0), GW - 1);
    py = min(max((int)qy, 0), GH - 1);
    return true;
}

// Wave-0 exclusive scan of src[0..T_TILES) into dst[0..T_TILES] (dst[T_TILES]=total).
// Works on LDS or global pointers. Caller must __syncthreads() afterwards.
__device__ __forceinline__ void tile_prefix_wave0(const unsigned* src, unsigned* dst) {
    int lane = threadIdx.x;
    if (lane < 64) {
        unsigned run = 0;
        for (int c = 0; c < T_TILES; c += 64) {
            int idx = c + lane;
            unsigned v = (idx < T_TILES) ? src[idx] : 0u;
            unsigned orig = v;
#pragma unroll
            for (int d = 1; d < 64; d <<= 1) {
                unsigned u = __shfl_up(v, d, 64);
                if (lane >= d) v += u;
            }
            if (idx < T_TILES) dst[idx] = run + (v - orig);  // exclusive
            run += __shfl(v, 63, 64);
        }
        if (lane == 0) dst[T_TILES] = run;
    }
}

// Record layout (u64): [key31 : 33] | [i16 : 17] | [local8 : 9] | [tile9 : 0]
//   key31 = f32 bits of max(fadd(z,3),0)  (positive f32 bits < 2^31; monotone;
//           yields EXACT reference h = clip(fmul(fadd(hmax,3),1/7)))
//   i16   = round(inten*256) clamped (8.8 fixed; exact integer summation)
__device__ __forceinline__ bool make_record(float4 p, unsigned long long& rec, int& tile) {
    int px, py;
    if (!bin_point(p.x, p.y, px, py)) return false;
    tile = (py >> 4) * TCOLS + (px >> 4);
    int local = ((py & 15) << 4) | (px & 15);
    unsigned key = __float_as_uint(fmaxf(__fadd_rn(p.z, 3.0f), 0.0f));
    int i16 = min(max((int)rintf(__fmul_rn(p.w, 256.0f)), 0), 65535);
    rec = ((unsigned long long)key << 33) | ((unsigned long long)(unsigned)i16 << 17) |
          ((unsigned long long)(unsigned)local << 9) | (unsigned long long)(unsigned)tile;
    return true;
}

// ---------------------------------------------------------------------------
// P1: fused hist + local-sort + staged scatter. One read of the point cloud.
// Each block owns staging segment [blockIdx*per_block, ...) — records grouped
// by tile via block-local counting sort (LDS buffer). Also zeros ch3/ch4.
// pref_t layout: pref_t[t * B1 + b] = block-local exclusive prefix (t<=T_TILES).
// ---------------------------------------------------------------------------
__global__ __launch_bounds__(256) void p1_kernel(const float4* __restrict__ pts, int n,
                                                 int per_block,
                                                 unsigned long long* __restrict__ staged,
                                                 unsigned* __restrict__ pref_t,
                                                 float* __restrict__ out) {
    __shared__ unsigned long long lbuf[256 * Q];  // transposed [j*256+tid]: conflict-free b64
    __shared__ unsigned cnt[T_TILES];
    __shared__ unsigned pref[T_TILES + 1];
    __shared__ unsigned cur[T_TILES];
    for (int t = threadIdx.x; t < T_TILES; t += 256) cnt[t] = 0;
    // zero ch3/ch4 (polyline stamps run in P2, stream-ordered after P1)
    float4* z4 = (float4*)(out + 3 * GHW);
    for (int j = blockIdx.x * 256 + (int)threadIdx.x; j < (2 * GHW) / 4; j += B1 * 256)
        z4[j] = make_float4(0.0f, 0.0f, 0.0f, 0.0f);
    __syncthreads();

    int start = blockIdx.x * per_block;
    int end = min(start + per_block, n);
    int nmine = 0;
    int i = start + (int)threadIdx.x;
    for (; i + 7 * 256 < end; i += 8 * 256) {
        float4 p[8];
#pragma unroll
        for (int j = 0; j < 8; ++j) p[j] = pts[i + j * 256];
#pragma unroll
        for (int j = 0; j < 8; ++j) {
            unsigned long long r;
            int tile;
            if (make_record(p[j], r, tile)) {
                lbuf[nmine * 256 + threadIdx.x] = r;
                ++nmine;
                atomicAdd(&cnt[tile], 1u);
            }
        }
    }
    for (; i < end; i += 256) {
        unsigned long long r;
        int tile;
        if (make_record(pts[i], r, tile)) {
            lbuf[nmine * 256 + threadIdx.x] = r;
            ++nmine;
            atomicAdd(&cnt[tile], 1u);
        }
    }
    __syncthreads();
    tile_prefix_wave0(cnt, pref);
    __syncthreads();
    for (int t = threadIdx.x; t < T_TILES; t += 256) cur[t] = pref[t];
    for (int t = threadIdx.x; t <= T_TILES; t += 256)
        pref_t[t * B1 + blockIdx.x] = pref[t];
    __syncthreads();
    size_t base = (size_t)blockIdx.x * (size_t)per_block;
    for (int j = 0; j < nmine; ++j) {
        unsigned long long r = lbuf[j * 256 + threadIdx.x];
        int tile = (int)(r & 511u);
        unsigned pos = atomicAdd(&cur[tile], 1u);
        staged[base + pos] = r;  // scattered 8B within 62KB block region; L2 merges
    }
}

// ---------------------------------------------------------------------------
// Polyline segment rasterizer, thread-per-segment (byte-identical math to the
// verified R3..R6 path).
// ---------------------------------------------------------------------------
__device__ void do_poly_segment(int seg, const float2* __restrict__ traj, int ntraj,
                                const float2* __restrict__ osm, int nosm,
                                const float* __restrict__ ego, float* __restrict__ out) {
    int ntseg = ntraj - 1;
    int noseg = nosm - 1;
    if (seg >= ntseg + noseg) return;
    const float2* pts;
    float* out_ch;
    bool use_ego;
    if (seg < ntseg) {
        pts = traj + seg;
        out_ch = out + 3 * GHW;
        use_ego = false;
    } else {
        pts = osm + (seg - ntseg);
        out_ch = out + 4 * GHW;
        use_ego = true;
    }
    float2 P0 = pts[0];
    float2 P1 = pts[1];
    if (use_ego) {
        float yaw = ego[2];
        float cy = cosf(-yaw), sy = sinf(-yaw);
        float ex = ego[0], ey = ego[1];
        float d0x = __fsub_rn(P0.x, ex), d0y = __fsub_rn(P0.y, ey);
        float d1x = __fsub_rn(P1.x, ex), d1y = __fsub_rn(P1.y, ey);
        P0.x = __fsub_rn(__fmul_rn(d0x, cy), __fmul_rn(d0y, sy));
        P0.y = __fadd_rn(__fmul_rn(d0x, sy), __fmul_rn(d0y, cy));
        P1.x = __fsub_rn(__fmul_rn(d1x, cy), __fmul_rn(d1y, sy));
        P1.y = __fadd_rn(__fmul_rn(d1x, sy), __fmul_rn(d1y, cy));
    }
    double ax = trunc(__ddiv_rn(__dadd_rn((double)P0.x, 20.0), 0.1));
    double ay = trunc(__ddiv_rn(__dadd_rn((double)P0.y, 10.0), 0.1));
    double bx = trunc(__ddiv_rn(__dadd_rn((double)P1.x, 20.0), 0.1));
    double by = trunc(__ddiv_rn(__dadd_rn((double)P1.y, 10.0), 0.1));
    bool inA = (ax >= 0.0) && (ax < (double)GW) && (ay >= 0.0) && (ay < (double)GH);
    bool inB = (bx >= 0.0) && (bx < (double)GW) && (by >= 0.0) && (by < (double)GH);
    if (!(inA || inB)) return;
    ax = fmin(fmax(ax, 0.0), (double)(GW - 1));
    ay = fmin(fmax(ay, 0.0), (double)(GH - 1));
    bx = fmin(fmax(bx, 0.0), (double)(GW - 1));
    by = fmin(fmax(by, 0.0), (double)(GH - 1));
    double dx = __dsub_rn(bx, ax);
    double dy = __dsub_rn(by, ay);
    double dmax = fmax(fabs(dx), fabs(dy));
    double denom = fmax(dmax, 1.0);
    int kmax = (int)dmax;
    for (int k = 0; k <= kmax; ++k) {
        double t = __ddiv_rn(fmin((double)k, dmax), denom);
        double ptx = __dadd_rn(ax, __dmul_rn(t, dx));
        double pty = __dadd_rn(ay, __dmul_rn(t, dy));
        int cx = (int)rint(ptx);  // half-to-even
        int cc = (int)rint(pty);
#pragma unroll
        for (int oy = -1; oy <= 1; ++oy) {
#pragma unroll
            for (int ox = -1; ox <= 1; ++ox) {
                int xx = cx + ox;
                int yy = cc + oy;
                if (xx < 0) xx += GW;  // JAX wraps negatives, drops OOB
                if (yy < 0) yy += GH;
                if (xx >= 0 && xx < GW && yy >= 0 && yy < GH) {
                    out_ch[yy * GW + xx] = 1.0f;
                }
            }
        }
    }
}

// ---------------------------------------------------------------------------
// P2: blocks [0, T_TILES) gather their tile's records from the 512 per-block
// chunks, LDS-accumulate, finalize; blocks [T_TILES,...) do polylines.
// ic packs (cnt << 40) | sum_i16 — overflow impossible: 4e6*65280 < 2^40.
// ---------------------------------------------------------------------------
__global__ __launch_bounds__(256) void p2_kernel(const unsigned long long* __restrict__ staged,
                                                 const unsigned* __restrict__ pref_t,
                                                 int per_block, float* __restrict__ out,
                                                 const float2* __restrict__ traj, int ntraj,
                                                 const float2* __restrict__ osm, int nosm,
                                                 const float* __restrict__ ego) {
    if (blockIdx.x >= T_TILES) {
        int seg = (blockIdx.x - T_TILES) * 256 + (int)threadIdx.x;
        do_poly_segment(seg, traj, ntraj, osm, nosm, ego, out);
        return;
    }
    __shared__ unsigned prefA[B1], prefB[B1];
    __shared__ unsigned zmax[256];          // f32 bits of max(z+3,0); 0 when empty
    __shared__ unsigned long long ic[256];  // (cnt<<40) | sum_i16
    int t = blockIdx.x;
    for (int b = threadIdx.x; b < B1; b += 256) {
        prefA[b] = pref_t[t * B1 + b];        // coalesced row reads
        prefB[b] = pref_t[(t + 1) * B1 + b];
    }
    zmax[threadIdx.x] = 0;
    ic[threadIdx.x] = 0;
    __syncthreads();
    for (int b = threadIdx.x; b < B1; b += 256) {
        size_t base = (size_t)b * (size_t)per_block;
        unsigned s = prefA[b], e = prefB[b];
        for (unsigned k = s; k < e; ++k) {
            unsigned long long r = staged[base + k];
            int local = (int)((r >> 9) & 255u);
            unsigned key = (unsigned)(r >> 33);
            unsigned long long v16 = (r >> 17) & 0xFFFFull;
            atomicMax(&zmax[local], key);
            atomicAdd(&ic[local], (1ull << 40) | v16);
        }
    }
    __syncthreads();
    int l = threadIdx.x;
    int trow = t / TCOLS, tcol = t % TCOLS;
    int gy = trow * 16 + (l >> 4);
    int gx = tcol * 16 + (l & 15);
    if (gy < GH) {
        const float inv7 = 1.0f / 7.0f;
        const float invlog129 = 1.0f / 4.8598124043616719e+00f;  // 1/log(129)
        unsigned long long v = ic[l];
        float h, ich, dd;
        if (v == 0) {
            h = fminf(fmaxf(__fmul_rn(3.0f, inv7), 0.0f), 1.0f);  // empty: clip(3/7)
            ich = 0.0f;
            dd = 0.0f;
        } else {
            unsigned cnt = (unsigned)(v >> 40);
            float sum16 = (float)(v & ((1ull << 40) - 1));        // exact (< 2^24)
            float keyf = __uint_as_float(zmax[l]);                // = max(fadd(hmax,3),0)
            h = fminf(fmaxf(__fmul_rn(keyf, inv7), 0.0f), 1.0f);  // exact reference h
            ich = fminf(__fdiv_rn(sum16, __fmul_rn((float)cnt, 65280.0f)), 1.0f);
            dd = fminf(__fmul_rn(log1pf((float)cnt), invlog129), 1.0f);
        }
        int idx = gy * GW + gx;
        out[0 * GHW + idx] = h;
        out[1 * GHW + idx] = ich;
        out[2 * GHW + idx] = dd;
    }
}

// Standalone polyline kernel (fallback path).
__global__ __launch_bounds__(256) void polylines_kernel(const float2* __restrict__ traj,
                                                        int ntraj,
                                                        const float2* __restrict__ osm, int nosm,
                                                        const float* __restrict__ ego,
                                                        float* __restrict__ out) {
    int seg = blockIdx.x * 256 + (int)threadIdx.x;
    do_poly_segment(seg, traj, ntraj, osm, nosm, ego, out);
}

// ======================== fallback (round-3) path ==========================
__global__ __launch_bounds__(256) void init_kernel(float* __restrict__ out) {
    int i = blockIdx.x * blockDim.x + threadIdx.x;
    if (i < GHW) {
        out[0 * GHW + i] = -INFINITY;
        out[1 * GHW + i] = 0.0f;
        out[2 * GHW + i] = 0.0f;
        out[3 * GHW + i] = 0.0f;
        out[4 * GHW + i] = 0.0f;
    }
}

__device__ __forceinline__ void atomicMaxFloat(float* addr, float val) {
    if (val >= 0.0f) {
        atomicMax((int*)addr, __float_as_int(val));
    } else {
        atomicMin((unsigned int*)addr, (unsigned int)__float_as_int(val));
    }
}

__global__ __launch_bounds__(256) void lidar_kernel(const float4* __restrict__ pts, int n,
                                                    float* __restrict__ out) {
    int i = blockIdx.x * blockDim.x + threadIdx.x;
    if (i >= n) return;
    float4 p = pts[i];
    int px, py;
    if (!bin_point(p.x, p.y, px, py)) return;
    int idx = py * GW + px;
    atomicMaxFloat(&out[0 * GHW + idx], p.z);
    atomicAdd(&out[1 * GHW + idx], p.w);
    atomicAdd(&out[2 * GHW + idx], 1.0f);
}

__global__ __launch_bounds__(256) void finalize_kernel(float* __restrict__ out) {
    int i = blockIdx.x * blockDim.x + threadIdx.x;
    if (i >= GHW) return;
    float hm = out[0 * GHW + i];
    float isum = out[1 * GHW + i];
    float c = out[2 * GHW + i];
    if (hm == -INFINITY) hm = 0.0f;
    const float inv7 = 1.0f / 7.0f;
    const float inv255 = 1.0f / 255.0f;
    const float invlog129 = 1.0f / 4.8598124043616719e+00f;
    float h = fminf(fmaxf(__fmul_rn(__fadd_rn(hm, 3.0f), inv7), 0.0f), 1.0f);
    float im = (c > 0.0f) ? __fdiv_rn(isum, fmaxf(c, 1.0f)) : 0.0f;
    float ich = fminf(fmaxf(__fmul_rn(im, inv255), 0.0f), 1.0f);
    float dd = fminf(fmaxf(__fmul_rn(log1pf(c), invlog129), 0.0f), 1.0f);
    out[0 * GHW + i] = h;
    out[1 * GHW + i] = ich;
    out[2 * GHW + i] = dd;
}

extern "C" void kernel_launch(void* const* d_in, const int* in_sizes, int n_in,
                              void* d_out, int out_size, void* d_ws, size_t ws_size,
                              hipStream_t stream) {
    const float* lidar = (const float*)d_in[0];
    const float* traj = (const float*)d_in[1];
    const float* osm = (const float*)d_in[2];
    const float* ego = (const float*)d_in[3];
    float* out = (float*)d_out;

    int n_lidar = in_sizes[0] / 4;
    int n_traj = in_sizes[1] / 2;
    int n_osm = in_sizes[2] / 2;
    int nseg = (n_traj - 1) + (n_osm - 1);
    int npb = (nseg + 255) / 256;

    int per_block = (n_lidar + B1 - 1) / B1;
    size_t staged_bytes = (size_t)B1 * (size_t)per_block * 8;
    size_t pref_bytes = (size_t)(T_TILES + 1) * B1 * 4;
    size_t need = staged_bytes + pref_bytes;

    if (ws_size >= need && per_block <= 256 * Q) {
        char* w = (char*)d_ws;
        unsigned long long* staged = (unsigned long long*)w;
        unsigned* pref_t = (unsigned*)(w + staged_bytes);

        p1_kernel<<<B1, 256, 0, stream>>>((const float4*)lidar, n_lidar, per_block, staged,
                                          pref_t, out);
        p2_kernel<<<T_TILES + npb, 256, 0, stream>>>(staged, pref_t, per_block, out,
                                                     (const float2*)traj, n_traj,
                                                     (const float2*)osm, n_osm, ego);
    } else {
        // fallback: verified round-3 atomic path
        init_kernel<<<(GHW + 255) / 256, 256, 0, stream>>>(out);
        lidar_kernel<<<(n_lidar + 255) / 256, 256, 0, stream>>>((const float4*)lidar, n_lidar,
                                                                out);
        finalize_kernel<<<(GHW + 255) / 256, 256, 0, stream>>>(out);
        polylines_kernel<<<(nseg + 255) / 256, 256, 0, stream>>>((const float2*)traj, n_traj,
                                                                 (const float2*)osm, n_osm, ego,
                                                                 out);
    }
}